// Round 4
// baseline (44.063 us; speedup 1.0000x reference)
//
#include <hip/hip_runtime.h>
#include <math.h>

#define K_TOP 16
#define D_DIM 1024
#define N_ROWS 2048           // 32 * 64 rows
#define OUT_F32 (N_ROWS * K_TOP * D_DIM)   // 33,554,432 floats

typedef float f32x4 __attribute__((ext_vector_type(4)));

// ---------------- K0: pure streaming zero-fill of d_out -------------------
// 2048 blocks x 256 threads, 16 f32x4 stores each = 134 MB. fillBuffer-like.
__global__ __launch_bounds__(256) void zero_fill_kernel(float* __restrict__ out)
{
    f32x4* o4 = reinterpret_cast<f32x4*>(out);
    const int base = blockIdx.x * 256 + threadIdx.x;   // f32x4 index
    const f32x4 z = {0.f, 0.f, 0.f, 0.f};
    #pragma unroll
    for (int i = 0; i < 16; ++i) {
        o4[(size_t)base + (size_t)i * (2048 * 256)] = z;
    }
}

// ---------------- K1: selection + scatter of the 16 ones ------------------
// One wave per row q. Lane owns d = lane*16 + j (coalesced f32x4 loads).
// 16 rounds of {per-lane masked argmax -> 64-lane butterfly argmax},
// tie-break prefers smaller global index. Then rank-sort ascending by index
// and store out[q][rank][sel] = 1.0f (16 scattered 4B stores per row).
__global__ __launch_bounds__(256) void select_scatter_kernel(
    const float* __restrict__ logits,  // (64, 1024)
    const float* __restrict__ gn,      // (32, 64, 1024)
    float* __restrict__ out)           // (32, 64, 16, 1024)
{
    const int tid  = threadIdx.x;
    const int lane = tid & 63;
    const int wave = tid >> 6;
    const int q    = blockIdx.x * 4 + wave;
    const int r    = q & 63;

    // ---- load + perturb: lane owns 16 consecutive elements (64 B) ----
    float v[16];
    {
        const f32x4* l4 = reinterpret_cast<const f32x4*>(
            logits + (size_t)r * D_DIM + lane * 16);
        const f32x4* g4 = reinterpret_cast<const f32x4*>(
            gn + (size_t)q * D_DIM + lane * 16);
        #pragma unroll
        for (int c = 0; c < 4; ++c) {
            const f32x4 a = l4[c];
            const f32x4 b = g4[c];
            v[c * 4 + 0] = a.x + b.x;
            v[c * 4 + 1] = a.y + b.y;
            v[c * 4 + 2] = a.z + b.z;
            v[c * 4 + 3] = a.w + b.w;
        }
    }

    // ---- 16 rounds of wave-wide argmax ----
    unsigned chosen = 0;   // bitmask of already-taken j's in THIS lane
    int my_sel = 0;        // lane k ends up holding round-k winner's index
    for (int round = 0; round < K_TOP; ++round) {
        float bv = -INFINITY;
        int   bi = 0x7fffffff;
        #pragma unroll
        for (int j = 0; j < 16; ++j) {
            if (!(chosen & (1u << j))) {
                // strict > keeps smaller j (= smaller global index) on tie
                if (v[j] > bv) { bv = v[j]; bi = lane * 16 + j; }
            }
        }
        #pragma unroll
        for (int off = 32; off > 0; off >>= 1) {
            const float ov = __shfl_xor(bv, off);
            const int   oi = __shfl_xor(bi, off);
            if (ov > bv || (ov == bv && oi < bi)) { bv = ov; bi = oi; }
        }
        if (lane == (bi >> 4)) chosen |= 1u << (bi & 15);  // owner retires it
        if (lane == round)     my_sel = bi;
    }

    // ---- rank among the 16 winners = ascending index order ----
    int rank = 0;
    #pragma unroll
    for (int j = 0; j < K_TOP; ++j) {
        const int other = __shfl(my_sel, j);
        rank += (other < my_sel) ? 1 : 0;
    }

    // ---- scatter the ones: out[q][rank][my_sel] = 1 ----
    if (lane < K_TOP) {
        out[(size_t)q * (K_TOP * D_DIM) + (size_t)rank * D_DIM + my_sel] = 1.0f;
    }
}

extern "C" void kernel_launch(void* const* d_in, const int* in_sizes, int n_in,
                              void* d_out, int out_size, void* d_ws, size_t ws_size,
                              hipStream_t stream) {
    const float* logits = (const float*)d_in[0];  // (64, 1024) f32
    const float* gn     = (const float*)d_in[1];  // (32, 64, 1024) f32
    float* out          = (float*)d_out;          // (32, 64, 16, 1024) f32

    // K0: zero everything (pure streaming store, fillBuffer-like).
    zero_fill_kernel<<<dim3(2048), dim3(256), 0, stream>>>(out);
    // K1: top-16 select + scatter 16 ones per row (runs after K0 on stream).
    select_scatter_kernel<<<dim3(N_ROWS / 4), dim3(256), 0, stream>>>(
        logits, gn, out);
}

// Round 5
// 33.194 us; speedup vs baseline: 1.3274x; 1.3274x over previous
//
#include <hip/hip_runtime.h>
#include <math.h>

#define K_TOP 16
#define D_DIM 1024
#define N_ROWS 2048                       // 32 * 64 rows

typedef float f32x4 __attribute__((ext_vector_type(4)));

// One block (256 thr) per row q:
//   waves 1..3: immediately zero k-rows 0..11 (48 KB) — independent of
//               selection, issues from cycle ~0.
//   wave 0:     load logits+gn (f32x4, lane owns d=lane*16+j), 16 rounds of
//               {per-lane masked argmax -> 64-lane butterfly}, rank-sort
//               ascending by index, then zero k-rows 12..15 (16 KB).
//   barrier, then wave 0 lanes 0..15 scatter the 16 ones (4 B stores into
//   lines still dirty in L2).
// No LDS; selection state lives entirely in wave-0 registers.
__global__ __launch_bounds__(256) void dps_topk_kernel(
    const float* __restrict__ logits,  // (64, 1024)
    const float* __restrict__ gn,      // (32, 64, 1024)
    float* __restrict__ out)           // (32, 64, 16, 1024)
{
    const int tid  = threadIdx.x;
    const int lane = tid & 63;
    const int wave = tid >> 6;
    const int q    = blockIdx.x;
    const int r    = q & 63;

    float* orow = out + (size_t)q * (K_TOP * D_DIM);
    f32x4* o4   = reinterpret_cast<f32x4*>(orow);
    const f32x4 z = {0.f, 0.f, 0.f, 0.f};

    int my_sel = 0, rank = 0;

    if (wave != 0) {
        // Zero k-rows (wave-1)*4 .. (wave-1)*4+3 : 1024 f32x4 per wave.
        f32x4* base = o4 + (wave - 1) * 1024 + lane;
        #pragma unroll
        for (int i = 0; i < 16; ++i) base[i * 64] = z;
    } else {
        // ---- load + perturb: lane owns 16 consecutive elements (64 B) ----
        float v[16];
        {
            const f32x4* l4 = reinterpret_cast<const f32x4*>(
                logits + (size_t)r * D_DIM + lane * 16);
            const f32x4* g4 = reinterpret_cast<const f32x4*>(
                gn + (size_t)q * D_DIM + lane * 16);
            #pragma unroll
            for (int c = 0; c < 4; ++c) {
                const f32x4 a = l4[c];
                const f32x4 b = g4[c];
                v[c * 4 + 0] = a.x + b.x;
                v[c * 4 + 1] = a.y + b.y;
                v[c * 4 + 2] = a.z + b.z;
                v[c * 4 + 3] = a.w + b.w;
            }
        }

        // ---- 16 rounds of wave-wide argmax ----
        unsigned chosen = 0;   // bitmask of already-taken j's in THIS lane
        for (int round = 0; round < K_TOP; ++round) {
            float bv = -INFINITY;
            int   bi = 0x7fffffff;
            #pragma unroll
            for (int j = 0; j < 16; ++j) {
                if (!(chosen & (1u << j))) {
                    // strict > keeps smaller j (=smaller index) on ties
                    if (v[j] > bv) { bv = v[j]; bi = lane * 16 + j; }
                }
            }
            #pragma unroll
            for (int off = 32; off > 0; off >>= 1) {
                const float ov = __shfl_xor(bv, off);
                const int   oi = __shfl_xor(bi, off);
                if (ov > bv || (ov == bv && oi < bi)) { bv = ov; bi = oi; }
            }
            if (lane == (bi >> 4)) chosen |= 1u << (bi & 15);
            if (lane == round)     my_sel = bi;
        }

        // ---- rank among the 16 winners = ascending index order ----
        #pragma unroll
        for (int j = 0; j < K_TOP; ++j) {
            const int other = __shfl(my_sel, j);
            rank += (other < my_sel) ? 1 : 0;
        }

        // ---- zero k-rows 12..15 (same store volume as other waves) ----
        f32x4* base = o4 + 3 * 1024 + lane;
        #pragma unroll
        for (int i = 0; i < 16; ++i) base[i * 64] = z;
    }

    __syncthreads();   // all zeros of this row's block landed

    // ---- scatter the 16 ones: out[q][rank][my_sel] = 1 ----
    if (wave == 0 && lane < K_TOP) {
        orow[rank * D_DIM + my_sel] = 1.0f;
    }
}

extern "C" void kernel_launch(void* const* d_in, const int* in_sizes, int n_in,
                              void* d_out, int out_size, void* d_ws, size_t ws_size,
                              hipStream_t stream) {
    const float* logits = (const float*)d_in[0];  // (64, 1024) f32
    const float* gn     = (const float*)d_in[1];  // (32, 64, 1024) f32
    float* out          = (float*)d_out;          // (32, 64, 16, 1024) f32

    dps_topk_kernel<<<dim3(N_ROWS), dim3(256), 0, stream>>>(logits, gn, out);
}